// Round 1
// baseline (8400.715 us; speedup 1.0000x reference)
//
#include <hip/hip_runtime.h>
#include <cstdint>
#include <cstddef>

// Problem constants (fixed by the reference).
#define B_   2048
#define T_   100
#define U_   512
#define NG_  2048   // 4*U
#define C_   10

typedef __attribute__((ext_vector_type(8))) short   short8;
typedef __attribute__((ext_vector_type(4))) float   floatx4;
typedef unsigned short ushort_t;

__device__ inline ushort_t f2bf(float f){
  unsigned u = __float_as_uint(f);
  unsigned r = (u + 0x7FFFu + ((u >> 16) & 1u)) >> 16;   // RNE
  return (ushort_t)r;
}
__device__ inline float bf2f(ushort_t b){ return __uint_as_float(((unsigned)b) << 16); }

__device__ inline float sigm(float x){ return 1.0f / (1.0f + __expf(-x)); }
__device__ inline float tanh_fast(float x){
  float a = fabsf(x);
  float e = __expf(-2.0f * a);          // no overflow: e in (0,1]
  float r = (1.0f - e) / (1.0f + e);
  return copysignf(r, x);
}

// Column permutation: permuted col p -> original gate-major col.
// Tile T (128 cols) owns u in [T*32, T*32+32); within tile: two 64-col halves
// (one per wave_n), each half = 4 gates x 16 u's, gate-major in 16-col groups.
__device__ inline int orig_col(int p){
  int Tt  = p >> 7;
  int loc = p & 127;
  int half = loc >> 6;
  int loc2 = loc & 63;
  int gate = loc2 >> 4;
  int uu   = (half << 4) | (loc2 & 15);
  return gate * U_ + Tt * 32 + uu;
}

#define AS1(p) ((const __attribute__((address_space(1))) void*)(p))
#define AS3(p) ((__attribute__((address_space(3))) void*)(p))

// ---------------------------------------------------------------------------
// One-time (per launch) weight repack: fp32 -> bf16, B^T (n-major) layout with
// gate-interleaved column permutation. Also permuted biases (fp32) and W0 row.
// ---------------------------------------------------------------------------
__global__ void convert_weights(
    const float* __restrict__ W0, const float* __restrict__ U0, const float* __restrict__ b0,
    const float* __restrict__ W1, const float* __restrict__ U1, const float* __restrict__ b1,
    const float* __restrict__ W2, const float* __restrict__ U2, const float* __restrict__ b2,
    ushort_t* __restrict__ Bt0, ushort_t* __restrict__ Bt1, ushort_t* __restrict__ Bt2,
    float* __restrict__ W0p, float* __restrict__ biasp)
{
  const int N0 = NG_ * 512;     // Bt0 elements
  const int N1 = NG_ * 1024;    // Bt1/Bt2 elements
  const int total = N0 + 2 * N1 + NG_ + 3 * NG_;
  int idx = blockIdx.x * 256 + threadIdx.x;
  if (idx >= total) return;

  if (idx < N0){
    int p = idx >> 9, k = idx & 511;
    Bt0[idx] = f2bf(U0[(size_t)k * NG_ + orig_col(p)]);
  } else if (idx < N0 + N1){
    int j = idx - N0; int p = j >> 10, k = j & 1023;
    int oc = orig_col(p);
    float v = (k < 512) ? W1[(size_t)k * NG_ + oc] : U1[(size_t)(k - 512) * NG_ + oc];
    Bt1[j] = f2bf(v);
  } else if (idx < N0 + 2 * N1){
    int j = idx - N0 - N1; int p = j >> 10, k = j & 1023;
    int oc = orig_col(p);
    float v = (k < 512) ? W2[(size_t)k * NG_ + oc] : U2[(size_t)(k - 512) * NG_ + oc];
    Bt2[j] = f2bf(v);
  } else if (idx < N0 + 2 * N1 + NG_){
    int p = idx - N0 - 2 * N1;
    W0p[p] = W0[orig_col(p)];
  } else {
    int j = idx - N0 - 2 * N1 - NG_;
    int l = j >> 11, p = j & 2047;
    const float* bs = (l == 0) ? b0 : (l == 1) ? b1 : b2;
    biasp[j] = bs[orig_col(p)];
  }
}

// ---------------------------------------------------------------------------
// Fused GEMM (bf16 MFMA) + LSTM cell for one (timestep, layer).
//   z[b, p] = sum_k A[b,k] * Bt[p,k]   (A = h_below | h_prev, bf16)
// 128x128 tile, 256 threads = 2x2 waves, each wave 4x4 frags of 16x16x32.
// Epilogue: per-lane gate quad (i,f,g,o) -> cell -> masked h (bf16) + c (fp32).
// ---------------------------------------------------------------------------
template<int NPHASE, bool IS_L0>
__global__ __launch_bounds__(256) void lstm_step(
    const ushort_t* __restrict__ A0,   // phase-0 A (h_below, or h_prev if NPHASE==1)
    const ushort_t* __restrict__ A1,   // phase-1 A (h_prev)
    const ushort_t* __restrict__ Bt,   // (2048 x NPHASE*512) bf16, n-major
    const float* __restrict__ biasp,   // permuted bias (2048)
    const float* __restrict__ W0p,     // permuted W0 row (L0 only)
    const float* __restrict__ x,       // (B,T) fp32 (L0 only)
    const int* __restrict__ mask,      // (B,T) int32
    float* __restrict__ cbuf,          // (B,U) fp32, in/out
    const ushort_t* __restrict__ hprev,// this layer's previous h (for mask carry)
    ushort_t* __restrict__ hout,       // (B,U) bf16 out
    int t)
{
  __shared__ __align__(16) ushort_t tA[128 * 32];
  __shared__ __align__(16) ushort_t tB[128 * 32];

  const int tid  = threadIdx.x;
  const int wv   = tid >> 6;
  const int lane = tid & 63;
  const int qd   = lane >> 4;     // quad 0..3
  const int l16  = lane & 15;
  const int wave_m = wv >> 1;     // 0..1
  const int wave_n = wv & 1;      // 0..1
  const int mt = blockIdx.x >> 4, nt = blockIdx.x & 15;
  const int m0 = mt * 128, n0 = nt * 128;
  const int K  = NPHASE * 512;

  floatx4 acc[4][4];
  #pragma unroll
  for (int i = 0; i < 4; ++i)
    #pragma unroll
    for (int j = 0; j < 4; ++j) acc[i][j] = (floatx4){0.f, 0.f, 0.f, 0.f};

  #pragma unroll
  for (int ph = 0; ph < NPHASE; ++ph){
    const ushort_t* A = (NPHASE == 2 && ph == 1) ? A1 : A0;
    for (int k0 = 0; k0 < 512; k0 += 32){
      // Stage A-tile (128x32) and B-tile (128x32) via direct-to-LDS 16B loads.
      // chunk i = cc2*256 + wv*64 + lane; row = i>>2, 16B col-chunk = i&3.
      #pragma unroll
      for (int cc2 = 0; cc2 < 2; ++cc2){
        int i  = cc2 * 256 + wv * 64 + lane;
        int r  = i >> 2, cc = i & 3;
        const ushort_t* ga = A + (size_t)(m0 + r) * U_ + k0 + cc * 8;
        __builtin_amdgcn_global_load_lds(AS1(ga), AS3(&tA[(cc2 * 256 + wv * 64) * 8]), 16, 0, 0);
        const ushort_t* gb = Bt + (size_t)(n0 + r) * K + ph * 512 + k0 + cc * 8;
        __builtin_amdgcn_global_load_lds(AS1(gb), AS3(&tB[(cc2 * 256 + wv * 64) * 8]), 16, 0, 0);
      }
      __syncthreads();

      short8 af[4], bfr[4];
      #pragma unroll
      for (int wm = 0; wm < 4; ++wm)
        af[wm] = *(const short8*)&tA[(wave_m * 64 + wm * 16 + l16) * 32 + qd * 8];
      #pragma unroll
      for (int wn = 0; wn < 4; ++wn)
        bfr[wn] = *(const short8*)&tB[(wave_n * 64 + wn * 16 + l16) * 32 + qd * 8];
      #pragma unroll
      for (int wm = 0; wm < 4; ++wm)
        #pragma unroll
        for (int wn = 0; wn < 4; ++wn)
          acc[wm][wn] = __builtin_amdgcn_mfma_f32_16x16x32_bf16(af[wm], bfr[wn], acc[wm][wn], 0, 0, 0);
      __syncthreads();
    }
  }

  // ---- epilogue: LSTM cell, fully in-register per lane ----
  // This lane owns u = nt*32 + wave_n*16 + l16 for 16 batch rows; frag wn = gate.
  const int u  = nt * 32 + wave_n * 16 + l16;
  const int pb = nt * 128 + wave_n * 64 + l16;
  const float bi = biasp[pb], bf_ = biasp[pb + 16], bg = biasp[pb + 32], bo = biasp[pb + 48];
  float wi = 0.f, wf = 0.f, wg = 0.f, wo = 0.f;
  if (IS_L0){ wi = W0p[pb]; wf = W0p[pb + 16]; wg = W0p[pb + 32]; wo = W0p[pb + 48]; }

  #pragma unroll
  for (int wm = 0; wm < 4; ++wm){
    #pragma unroll
    for (int reg = 0; reg < 4; ++reg){
      int b = m0 + wave_m * 64 + wm * 16 + qd * 4 + reg;
      float zi = acc[wm][0][reg] + bi;
      float zf = acc[wm][1][reg] + bf_;
      float zg = acc[wm][2][reg] + bg;
      float zo = acc[wm][3][reg] + bo;
      if (IS_L0){
        float xv = x[(size_t)b * T_ + t];
        zi += xv * wi; zf += xv * wf; zg += xv * wg; zo += xv * wo;
      }
      int mk = mask[(size_t)b * T_ + t];
      size_t su = (size_t)b * U_ + u;
      float c_old = cbuf[su];
      float i_ = sigm(zi), f_ = sigm(zf), g_ = tanh_fast(zg), o_ = sigm(zo);
      float c_new = f_ * c_old + i_ * g_;
      float h_new = o_ * tanh_fast(c_new);
      ushort_t hb = mk ? f2bf(h_new) : hprev[su];
      cbuf[su] = mk ? c_new : c_old;
      hout[su] = hb;
    }
  }
}

// ---------------------------------------------------------------------------
// Head: logits = h2 @ Wd + bd, softmax. One wave per batch row.
// ---------------------------------------------------------------------------
__global__ __launch_bounds__(256) void head_softmax(
    const ushort_t* __restrict__ h2, const float* __restrict__ Wd,
    const float* __restrict__ bd, float* __restrict__ out)
{
  int wv = threadIdx.x >> 6, lane = threadIdx.x & 63;
  int row = blockIdx.x * 4 + wv;
  const ushort_t* hr = h2 + (size_t)row * U_;

  float acc[C_];
  #pragma unroll
  for (int c = 0; c < C_; ++c) acc[c] = 0.f;

  short8 hv = *(const short8*)&hr[lane * 8];
  #pragma unroll
  for (int j = 0; j < 8; ++j){
    float hf = bf2f((ushort_t)hv[j]);
    int k = lane * 8 + j;
    #pragma unroll
    for (int c = 0; c < C_; ++c) acc[c] += hf * Wd[k * C_ + c];
  }
  #pragma unroll
  for (int c = 0; c < C_; ++c){
    float v = acc[c];
    #pragma unroll
    for (int off = 32; off > 0; off >>= 1) v += __shfl_xor(v, off);
    acc[c] = v + bd[c];
  }
  float mx = acc[0];
  #pragma unroll
  for (int c = 1; c < C_; ++c) mx = fmaxf(mx, acc[c]);
  float e[C_]; float s = 0.f;
  #pragma unroll
  for (int c = 0; c < C_; ++c){ e[c] = __expf(acc[c] - mx); s += e[c]; }
  float inv = 1.0f / s;
  if (lane == 0){
    #pragma unroll
    for (int c = 0; c < C_; ++c) out[(size_t)row * C_ + c] = e[c] * inv;
  }
}

// ---------------------------------------------------------------------------
extern "C" void kernel_launch(void* const* d_in, const int* in_sizes, int n_in,
                              void* d_out, int out_size, void* d_ws, size_t ws_size,
                              hipStream_t stream)
{
  const float* x  = (const float*)d_in[0];
  const int*  mask= (const int*)  d_in[1];
  const float* W0 = (const float*)d_in[2];
  const float* U0 = (const float*)d_in[3];
  const float* b0 = (const float*)d_in[4];
  const float* W1 = (const float*)d_in[5];
  const float* U1 = (const float*)d_in[6];
  const float* b1 = (const float*)d_in[7];
  const float* W2 = (const float*)d_in[8];
  const float* U2 = (const float*)d_in[9];
  const float* b2 = (const float*)d_in[10];
  const float* Wd = (const float*)d_in[11];
  const float* bd = (const float*)d_in[12];
  float* out = (float*)d_out;

  char* ws = (char*)d_ws;
  size_t off = 0;
  auto alloc = [&](size_t sz) -> char* {
    char* p = ws + off; off = (off + sz + 255) & ~(size_t)255; return p;
  };
  ushort_t* Bt0  = (ushort_t*)alloc((size_t)NG_ * 512 * 2);
  ushort_t* Bt1  = (ushort_t*)alloc((size_t)NG_ * 1024 * 2);
  ushort_t* Bt2  = (ushort_t*)alloc((size_t)NG_ * 1024 * 2);
  float*    W0p  = (float*)alloc((size_t)NG_ * 4);
  float*    biasp= (float*)alloc((size_t)3 * NG_ * 4);

  // State: [hA x3 (parity0 bf16)] [c x3 (fp32)] [hB x3 (parity1 bf16)]
  const size_t hsz = (size_t)B_ * U_ * 2;
  const size_t csz = (size_t)B_ * U_ * 4;
  char* state = alloc(3 * hsz + 3 * csz + 3 * hsz);
  ushort_t* hA[3]; float* cb[3]; ushort_t* hB[3];
  {
    char* pp = state;
    for (int l = 0; l < 3; ++l){ hA[l] = (ushort_t*)pp; pp += hsz; }
    for (int l = 0; l < 3; ++l){ cb[l] = (float*)pp;    pp += csz; }
    for (int l = 0; l < 3; ++l){ hB[l] = (ushort_t*)pp; pp += hsz; }
  }
  // Zero initial h (parity0) and c in one contiguous memset.
  hipMemsetAsync(state, 0, 3 * hsz + 3 * csz, stream);

  const int total = NG_ * 512 + 2 * NG_ * 1024 + NG_ + 3 * NG_;
  convert_weights<<<(total + 255) / 256, 256, 0, stream>>>(
      W0, U0, b0, W1, U1, b1, W2, U2, b2, Bt0, Bt1, Bt2, W0p, biasp);

  for (int t = 0; t < T_; ++t){
    ushort_t** hp = (t & 1) ? hB : hA;   // previous-timestep h
    ushort_t** hn = (t & 1) ? hA : hB;   // this-timestep h
    lstm_step<1, true ><<<256, 256, 0, stream>>>(hp[0], nullptr, Bt0, biasp,
        W0p, x, mask, cb[0], hp[0], hn[0], t);
    lstm_step<2, false><<<256, 256, 0, stream>>>(hn[0], hp[1], Bt1, biasp + NG_,
        nullptr, nullptr, mask, cb[1], hp[1], hn[1], t);
    lstm_step<2, false><<<256, 256, 0, stream>>>(hn[1], hp[2], Bt2, biasp + 2 * NG_,
        nullptr, nullptr, mask, cb[2], hp[2], hn[2], t);
  }
  // T=100 even -> final h of layer 2 is in hA[2].
  head_softmax<<<B_ / 4, 256, 0, stream>>>(hA[2], Wd, bd, out);
}